// Round 1
// baseline (171.239 us; speedup 1.0000x reference)
//
#include <hip/hip_runtime.h>
#include <math.h>

#define T_LEN 1024
#define VV 512
#define BB 64
#define NB 16

__device__ constexpr int KB[NB] = {1,2,3,4,5,6,7,8,12,16,24,32,48,64,96,128};
#define ANG_STEP 0.006135923151542565f   // 2*pi/1024

// ---------------- Kernel 1: partial 16-bin DFT over a t-chunk ----------------
// grid (BB, TC), block 256. Thread owns v0=2*tid, v0+1. Rotation recurrence in regs.
// Partials layout: xp[((b*TC + tc)*32 + q)*VV + v], q in [0,16)=re_j, [16,32)=im_j
__global__ __launch_bounds__(256) void k_dft_partial(const float* __restrict__ x,
                                                     float* __restrict__ xpart,
                                                     int tc_count, int tlen) {
    const int b   = blockIdx.x;
    const int tc  = blockIdx.y;
    const int tid = threadIdx.x;
    const int t0  = tc * tlen;

    float xr0[NB], xi0[NB], xr1[NB], xi1[NB];
    float c[NB], s[NB], cw[NB], sw[NB];
#pragma unroll
    for (int j = 0; j < NB; ++j) {
        xr0[j] = xi0[j] = xr1[j] = xi1[j] = 0.0f;
        int n0 = (KB[j] * t0) & (T_LEN - 1);
        sincosf(ANG_STEP * (float)n0, &s[j], &c[j]);
        sincosf(ANG_STEP * (float)KB[j], &sw[j], &cw[j]);
    }

    const float2* xrd = (const float2*)(x + (size_t)b * T_LEN * VV + (size_t)t0 * VV) + tid;
    for (int t = 0; t < tlen; ++t) {
        float2 xv = xrd[(size_t)t * (VV / 2)];
#pragma unroll
        for (int j = 0; j < NB; ++j) {
            xr0[j] = fmaf(xv.x, c[j], xr0[j]);
            xi0[j] = fmaf(-xv.x, s[j], xi0[j]);
            xr1[j] = fmaf(xv.y, c[j], xr1[j]);
            xi1[j] = fmaf(-xv.y, s[j], xi1[j]);
            float cn = fmaf(c[j], cw[j], -(s[j] * sw[j]));   // rotate by e^{i*w_j}
            float sn = fmaf(s[j], cw[j],  (c[j] * sw[j]));
            c[j] = cn; s[j] = sn;
        }
    }

    float2* o = (float2*)(xpart + (size_t)(b * tc_count + tc) * 32 * VV) + tid;
#pragma unroll
    for (int j = 0; j < NB; ++j) {
        o[(size_t)j        * (VV / 2)] = make_float2(xr0[j], xr1[j]);
        o[(size_t)(NB + j) * (VV / 2)] = make_float2(xi0[j], xi1[j]);
    }
}

// ---------------- Kernel 2: reduce partials, apply gains -> H ----------------
// H layout: H[b][q][v], q: [0,16)=hl_re, [16,32)=-hl_im, [32,48)=hd_re, [48,64)=-hd_im
// (2/T scale folded in; ims pre-negated so k_apply is pure fmaf)
__global__ __launch_bounds__(256) void k_combine(const float* __restrict__ xpart,
                                                 const float* __restrict__ ger,
                                                 const float* __restrict__ gei,
                                                 const float* __restrict__ glr,
                                                 const float* __restrict__ gli,
                                                 float* __restrict__ H, int tc_count) {
    const int b   = blockIdx.x;
    const int tid = threadIdx.x;
    const int v0  = tid * 2;

    float Xr0[NB], Xi0[NB], Xr1[NB], Xi1[NB];
#pragma unroll
    for (int j = 0; j < NB; ++j) { Xr0[j] = Xi0[j] = Xr1[j] = Xi1[j] = 0.0f; }

    for (int tc = 0; tc < tc_count; ++tc) {
        const float2* p = (const float2*)(xpart + (size_t)(b * tc_count + tc) * 32 * VV) + tid;
#pragma unroll
        for (int j = 0; j < NB; ++j) {
            float2 a  = p[(size_t)j        * (VV / 2)];
            float2 bb = p[(size_t)(NB + j) * (VV / 2)];
            Xr0[j] += a.x;  Xr1[j] += a.y;
            Xi0[j] += bb.x; Xi1[j] += bb.y;
        }
    }

    const float scale = 2.0f / (float)T_LEN;
    float2* o = (float2*)(H + (size_t)b * 64 * VV) + tid;
#pragma unroll
    for (int j = 0; j < NB; ++j) {
        float er0 = ger[v0 * NB + j],       ei0 = gei[v0 * NB + j];
        float lr0 = glr[v0 * NB + j],       li0 = gli[v0 * NB + j];
        float er1 = ger[(v0 + 1) * NB + j], ei1 = gei[(v0 + 1) * NB + j];
        float lr1 = glr[(v0 + 1) * NB + j], li1 = gli[(v0 + 1) * NB + j];
        float dr0 = er0 - lr0, di0 = ei0 - li0;
        float dr1 = er1 - lr1, di1 = ei1 - li1;

        float hlre0 = (Xr0[j] * lr0 - Xi0[j] * li0) * scale;
        float hlim0 = (Xr0[j] * li0 + Xi0[j] * lr0) * scale;
        float hdre0 = (Xr0[j] * dr0 - Xi0[j] * di0) * scale;
        float hdim0 = (Xr0[j] * di0 + Xi0[j] * dr0) * scale;
        float hlre1 = (Xr1[j] * lr1 - Xi1[j] * li1) * scale;
        float hlim1 = (Xr1[j] * li1 + Xi1[j] * lr1) * scale;
        float hdre1 = (Xr1[j] * dr1 - Xi1[j] * di1) * scale;
        float hdim1 = (Xr1[j] * di1 + Xi1[j] * dr1) * scale;

        o[(size_t)j        * (VV / 2)] = make_float2(hlre0, hlre1);
        o[(size_t)(16 + j) * (VV / 2)] = make_float2(-hlim0, -hlim1);
        o[(size_t)(32 + j) * (VV / 2)] = make_float2(hdre0, hdre1);
        o[(size_t)(48 + j) * (VV / 2)] = make_float2(-hdim0, -hdim1);
    }
}

// ---------------- Kernel 3: synthesize + crossfade + add x ----------------
// grid (BB, 8) t-tiles of 128, block 256, thread owns v0=2*tid, v0+1.
__global__ __launch_bounds__(256) void k_apply(const float* __restrict__ x,
                                               const float* __restrict__ H,
                                               float* __restrict__ out) {
    const int b   = blockIdx.x;
    const int tb  = blockIdx.y;
    const int tid = threadIdx.x;
    const int TLEN = 128;
    const int t0  = tb * TLEN;

    __shared__ float2 tab[T_LEN];
    for (int i = tid; i < T_LEN; i += 256) {
        float ss, cc;
        sincosf(ANG_STEP * (float)i, &ss, &cc);
        tab[i] = make_float2(cc, ss);
    }
    __syncthreads();

    float hlre0[NB], nhlim0[NB], hdre0[NB], nhdim0[NB];
    float hlre1[NB], nhlim1[NB], hdre1[NB], nhdim1[NB];
    const float2* hp = (const float2*)(H + (size_t)b * 64 * VV) + tid;
#pragma unroll
    for (int j = 0; j < NB; ++j) {
        float2 a = hp[(size_t)j        * (VV / 2)]; hlre0[j]  = a.x; hlre1[j]  = a.y;
        float2 bq = hp[(size_t)(16 + j) * (VV / 2)]; nhlim0[j] = bq.x; nhlim1[j] = bq.y;
        float2 cq = hp[(size_t)(32 + j) * (VV / 2)]; hdre0[j]  = cq.x; hdre1[j]  = cq.y;
        float2 dq = hp[(size_t)(48 + j) * (VV / 2)]; nhdim0[j] = dq.x; nhdim1[j] = dq.y;
    }

    const float2* xrd = (const float2*)(x + ((size_t)b * T_LEN + t0) * VV) + tid;
    float2*       ow  = (float2*)(out + ((size_t)b * T_LEN + t0) * VV) + tid;

    for (int t = 0; t < TLEN; ++t) {
        const int tg = t0 + t;
        float2 xv = xrd[(size_t)t * (VV / 2)];
        float sl0 = 0.f, sd0 = 0.f, sl1 = 0.f, sd1 = 0.f;
#pragma unroll
        for (int j = 0; j < NB; ++j) {
            float2 cs = tab[(KB[j] * tg) & (T_LEN - 1)];
            sl0 = fmaf(hlre0[j], cs.x, sl0); sl0 = fmaf(nhlim0[j], cs.y, sl0);
            sd0 = fmaf(hdre0[j], cs.x, sd0); sd0 = fmaf(nhdim0[j], cs.y, sd0);
            sl1 = fmaf(hlre1[j], cs.x, sl1); sl1 = fmaf(nhlim1[j], cs.y, sl1);
            sd1 = fmaf(hdre1[j], cs.x, sd1); sd1 = fmaf(nhdim1[j], cs.y, sd1);
        }
        // early/late crossfade weight (FADE_START=487, FADE_END=537, width 50)
        float w = (tg < 487) ? 1.0f : ((tg < 537) ? (1.0f - (float)(tg - 487) * (1.0f / 50.0f)) : 0.0f);
        float2 ov;
        ov.x = xv.x + fmaf(w, sd0, sl0);
        ov.y = xv.y + fmaf(w, sd1, sl1);
        ow[(size_t)t * (VV / 2)] = ov;
    }
}

extern "C" void kernel_launch(void* const* d_in, const int* in_sizes, int n_in,
                              void* d_out, int out_size, void* d_ws, size_t ws_size,
                              hipStream_t stream) {
    (void)in_sizes; (void)n_in; (void)out_size;
    const float* x   = (const float*)d_in[0];
    const float* ger = (const float*)d_in[1];
    const float* gei = (const float*)d_in[2];
    const float* glr = (const float*)d_in[3];
    const float* gli = (const float*)d_in[4];
    float* out = (float*)d_out;

    // workspace: partials (BB*TC*32*VV floats) + H (BB*64*VV floats)
    int TC = 8;
    while (TC > 1 &&
           ((size_t)BB * TC * 32 * VV + (size_t)BB * 64 * VV) * sizeof(float) > ws_size) {
        TC >>= 1;
    }
    float* xpart = (float*)d_ws;
    float* H     = xpart + (size_t)BB * TC * 32 * VV;
    const int tlen = T_LEN / TC;

    k_dft_partial<<<dim3(BB, TC), 256, 0, stream>>>(x, xpart, TC, tlen);
    k_combine<<<dim3(BB), 256, 0, stream>>>(xpart, ger, gei, glr, gli, H, TC);
    k_apply<<<dim3(BB, 8), 256, 0, stream>>>(x, H, out);
}